// Round 1
// baseline (1688.010 us; speedup 1.0000x reference)
//
#include <hip/hip_runtime.h>
#include <math.h>

// ---------------------------------------------------------------------------
// QuantumAutoEncoder: Dense -> circuit(enc) -> Dense -> Dense -> circuit(dec)
//   -> Dense -> abs-normalize.
// Baseline: fp32 everywhere (no fp32 MFMA on CDNA4; precision headroom first,
// bf16x3-split MFMA is the planned follow-up).
// ---------------------------------------------------------------------------

#define B_SZ 4096
#define EMB 1024
#define NQ 10
#define NL 3

// ------------------------------ GEMM (fp32) --------------------------------
// C[M,N] = A[M,K] @ W[K,N] + bias[N]; 128x128 block tile, BK=16, 256 threads,
// 8x8 micro-tile per thread. Bounds-guarded for K=1000 / N=1000 edges.
#define BM 128
#define BN 128
#define BK 16

__global__ __launch_bounds__(256) void gemm_bias(
    const float* __restrict__ A, const float* __restrict__ Bw,
    const float* __restrict__ bias, float* __restrict__ C,
    int M, int N, int K)
{
    __shared__ float As[BK][BM];   // A tile transposed: As[kk][row]
    __shared__ float Bs[BK][BN];

    const int tid = threadIdx.x;        // 0..255
    const int tx = tid & 15;            // 16 x 16 thread grid
    const int ty = tid >> 4;
    const int blockRow = blockIdx.y * BM;
    const int blockCol = blockIdx.x * BN;

    float acc[8][8];
    #pragma unroll
    for (int i = 0; i < 8; ++i)
        #pragma unroll
        for (int j = 0; j < 8; ++j) acc[i][j] = 0.f;

    for (int k0 = 0; k0 < K; k0 += BK) {
        // Load A tile: BM*BK = 2048 elems, 8 contiguous-K elems per thread.
        #pragma unroll
        for (int i = 0; i < 8; ++i) {
            int l = tid * 8 + i;
            int row = l / BK, kk = l % BK;
            int gr = blockRow + row, gk = k0 + kk;
            As[kk][row] = (gr < M && gk < K) ? A[(size_t)gr * K + gk] : 0.f;
        }
        // Load B tile: BK*BN = 2048 elems, 8 contiguous-N elems per thread.
        #pragma unroll
        for (int i = 0; i < 8; ++i) {
            int l = tid * 8 + i;
            int kk = l / BN, col = l % BN;
            int gk = k0 + kk, gc = blockCol + col;
            Bs[kk][col] = (gk < K && gc < N) ? Bw[(size_t)gk * N + gc] : 0.f;
        }
        __syncthreads();

        #pragma unroll
        for (int kk = 0; kk < BK; ++kk) {
            float a[8], b[8];
            #pragma unroll
            for (int i = 0; i < 8; ++i) a[i] = As[kk][ty * 8 + i];
            #pragma unroll
            for (int j = 0; j < 8; ++j) b[j] = Bs[kk][tx * 8 + j];
            #pragma unroll
            for (int i = 0; i < 8; ++i)
                #pragma unroll
                for (int j = 0; j < 8; ++j)
                    acc[i][j] = fmaf(a[i], b[j], acc[i][j]);
        }
        __syncthreads();
    }

    #pragma unroll
    for (int i = 0; i < 8; ++i) {
        int gr = blockRow + ty * 8 + i;
        if (gr >= M) continue;
        #pragma unroll
        for (int j = 0; j < 8; ++j) {
            int gc = blockCol + tx * 8 + j;
            if (gc < N) C[(size_t)gr * N + gc] = acc[i][j] + bias[gc];
        }
    }
}

// --------------------------- Quantum circuit -------------------------------
// One block per batch item. 1024-amplitude complex state in LDS.
// AmplitudeEmbedding(normalize) + 3 StronglyEntanglingLayers + probs.
// Wire q <-> bit (9-q) of the flat index (row-major reshape, wire0 = MSB).
__global__ __launch_bounds__(256) void circuit_kernel(
    const float* __restrict__ X, float* __restrict__ P,
    const float* __restrict__ W)   // W: [NL, NQ, 3]
{
    __shared__ float re[1024];
    __shared__ float im[1024];
    __shared__ float red[4];

    const int b = blockIdx.x;
    const int tid = threadIdx.x;
    const float* xb = X + (size_t)b * 1024;

    // load + norm^2
    float local = 0.f;
    #pragma unroll
    for (int i = tid; i < 1024; i += 256) {
        float v = xb[i];
        re[i] = v; im[i] = 0.f;
        local += v * v;
    }
    #pragma unroll
    for (int off = 32; off > 0; off >>= 1) local += __shfl_down(local, off);
    if ((tid & 63) == 0) red[tid >> 6] = local;
    __syncthreads();
    float inv = 1.0f / sqrtf(red[0] + red[1] + red[2] + red[3]);
    #pragma unroll
    for (int i = tid; i < 1024; i += 256) re[i] *= inv;
    __syncthreads();

    for (int l = 0; l < NL; ++l) {
        // Rot(phi, theta, omega) on each wire
        for (int q = 0; q < NQ; ++q) {
            const float* wg = W + (l * NQ + q) * 3;
            float phi = wg[0], th = wg[1], om = wg[2];
            float ch = cosf(0.5f * th), sh = sinf(0.5f * th);
            float ap = 0.5f * (phi + om), am = 0.5f * (phi - om);
            float cap = cosf(ap), sap = sinf(ap);
            float cam = cosf(am), sam = sinf(am);
            // U = [[ea*c, -eb*s], [conj(eb)*s, conj(ea)*c]]
            float a_re =  cap * ch, a_im = -sap * ch;
            float b_re = -cam * sh, b_im = -sam * sh;
            float c_re =  cam * sh, c_im = -sam * sh;
            float d_re =  cap * ch, d_im =  sap * ch;

            int m = 9 - q, s = 1 << m;
            #pragma unroll 2
            for (int p = tid; p < 512; p += 256) {
                int i0 = ((p >> m) << (m + 1)) | (p & (s - 1));
                int i1 = i0 | s;
                float r0 = re[i0], u0 = im[i0];
                float r1 = re[i1], u1 = im[i1];
                re[i0] = a_re * r0 - a_im * u0 + b_re * r1 - b_im * u1;
                im[i0] = a_re * u0 + a_im * r0 + b_re * u1 + b_im * r1;
                re[i1] = c_re * r0 - c_im * u0 + d_re * r1 - d_im * u1;
                im[i1] = c_re * u0 + c_im * r0 + d_re * u1 + d_im * r1;
            }
            __syncthreads();
        }
        // CNOT ring: control q -> target (q + r) % NQ, applied in order
        int r = l % (NQ - 1) + 1;
        for (int q = 0; q < NQ; ++q) {
            int t = (q + r) % NQ;
            int sc = 1 << (9 - q), st = 1 << (9 - t);
            #pragma unroll 4
            for (int idx = tid; idx < 1024; idx += 256) {
                if ((idx & sc) && !(idx & st)) {
                    int j = idx | st;
                    float tr = re[idx]; re[idx] = re[j]; re[j] = tr;
                    float ti = im[idx]; im[idx] = im[j]; im[j] = ti;
                }
            }
            __syncthreads();
        }
    }

    float* pb = P + (size_t)b * 1024;
    #pragma unroll
    for (int i = tid; i < 1024; i += 256) {
        float r = re[i], u = im[i];
        pb[i] = r * r + u * u;
    }
}

// ------------------------- abs + row-normalize -----------------------------
__global__ __launch_bounds__(256) void absnorm_kernel(
    const float* __restrict__ X, float* __restrict__ out, int N)
{
    __shared__ float red[4];
    const int row = blockIdx.x;
    const int tid = threadIdx.x;
    const float* xr = X + (size_t)row * N;

    float s = 0.f;
    for (int i = tid; i < N; i += 256) s += fabsf(xr[i]);
    #pragma unroll
    for (int off = 32; off > 0; off >>= 1) s += __shfl_down(s, off);
    if ((tid & 63) == 0) red[tid >> 6] = s;
    __syncthreads();
    float inv = 1.0f / (red[0] + red[1] + red[2] + red[3]);
    for (int i = tid; i < N; i += 256)
        out[(size_t)row * N + i] = fabsf(xr[i]) * inv;
}

// ---------------------------------------------------------------------------
extern "C" void kernel_launch(void* const* d_in, const int* in_sizes, int n_in,
                              void* d_out, int out_size, void* d_ws, size_t ws_size,
                              hipStream_t stream)
{
    const float* inputs = (const float*)d_in[0];
    const float* wEnc   = (const float*)d_in[1];
    const float* wDec   = (const float*)d_in[2];
    const float* W0     = (const float*)d_in[3];
    const float* b0     = (const float*)d_in[4];
    const float* W1     = (const float*)d_in[5];
    const float* b1     = (const float*)d_in[6];
    const float* W2     = (const float*)d_in[7];
    const float* b2     = (const float*)d_in[8];
    const float* W3     = (const float*)d_in[9];
    const float* b3     = (const float*)d_in[10];
    float* out = (float*)d_out;

    // Workspace layout (fp32), buffers reused across stages:
    //   bufA: B*EMB      (x0, later x2)
    //   bufB: B*EMB      (probs_enc, later probs_dec)
    //   bufC: B*2*EMB    (x1, later x3[B,1000])
    float* bufA = (float*)d_ws;
    float* bufB = bufA + (size_t)B_SZ * EMB;
    float* bufC = bufB + (size_t)B_SZ * EMB;

    dim3 blk(256);
    auto grid = [](int n, int m) { return dim3((n + BN - 1) / BN, (m + BM - 1) / BM); };

    // x0 = inputs @ W0 + b0          [4096,1024], K=1000
    gemm_bias<<<grid(EMB, B_SZ), blk, 0, stream>>>(inputs, W0, b0, bufA, B_SZ, EMB, 1000);
    // probs_enc = circuit(x0, wEnc)  [4096,1024]
    circuit_kernel<<<B_SZ, 256, 0, stream>>>(bufA, bufB, wEnc);
    // x1 = probs_enc @ W1 + b1       [4096,2048], K=1024
    gemm_bias<<<grid(2 * EMB, B_SZ), blk, 0, stream>>>(bufB, W1, b1, bufC, B_SZ, 2 * EMB, EMB);
    // x2 = x1 @ W2 + b2              [4096,1024], K=2048
    gemm_bias<<<grid(EMB, B_SZ), blk, 0, stream>>>(bufC, W2, b2, bufA, B_SZ, EMB, 2 * EMB);
    // probs_dec = circuit(x2, wDec)  [4096,1024]
    circuit_kernel<<<B_SZ, 256, 0, stream>>>(bufA, bufB, wDec);
    // x3 = probs_dec @ W3 + b3       [4096,1000], K=1024
    gemm_bias<<<grid(1000, B_SZ), blk, 0, stream>>>(bufB, W3, b3, bufC, B_SZ, 1000, EMB);
    // out = |x3| / rowsum(|x3|)
    absnorm_kernel<<<B_SZ, 256, 0, stream>>>(bufC, out, 1000);
}

// Round 2
// 603.791 us; speedup vs baseline: 2.7957x; 2.7957x over previous
//
#include <hip/hip_runtime.h>
#include <math.h>

// ---------------------------------------------------------------------------
// QuantumAutoEncoder. Round 2: GEMMs on MFMA with bf16x3 split
// (C = Ah*Bh + Ah*Bl + Al*Bh, fp32 accumulate) for fp32-grade accuracy at
// bf16-MFMA rates. m97-style staging: global_load_lds width=16, 128x128 tile,
// BK=32, 512 threads (8 waves, 32x64 per wave). Circuits unchanged except the
// epilogue emits the hi/lo bf16 split directly.
// ---------------------------------------------------------------------------

#define B_SZ 4096
#define EMB 1024
#define NQ 10
#define NL 3

typedef __bf16 bf16x8 __attribute__((ext_vector_type(8)));
typedef float f32x4 __attribute__((ext_vector_type(4)));

__device__ __forceinline__ unsigned short f2bf_rne(float f) {
    unsigned int u = __float_as_uint(f);
    u += 0x7FFFu + ((u >> 16) & 1u);
    return (unsigned short)(u >> 16);
}
__device__ __forceinline__ float bf2f(unsigned short h) {
    return __uint_as_float(((unsigned int)h) << 16);
}

__device__ __forceinline__ void gll16(const void* g, void* l) {
    __builtin_amdgcn_global_load_lds(
        (const __attribute__((address_space(1))) void*)g,
        (__attribute__((address_space(3))) void*)l, 16, 0, 0);
}

// --------------------------- MFMA GEMM (bf16x3) ----------------------------
// C[M,Np] = (Ah+Al)[M,Kp] @ (Bh+Bl)^T[Np,Kp] + bias, all dims padded
// (M%128==0, Np%128==0, Kp%32==0). storeSplit: write hi/lo bf16 instead of f32.
#define GBM 128
#define GBN 128
#define GBK 32

__global__ __launch_bounds__(512) void gemm3_mfma(
    const unsigned short* __restrict__ Ah, const unsigned short* __restrict__ Al,
    const unsigned short* __restrict__ Bh, const unsigned short* __restrict__ Bl,
    const float* __restrict__ bias,
    float* __restrict__ C, unsigned short* __restrict__ Ch, unsigned short* __restrict__ Cl,
    int Kp, int Np, int storeSplit)
{
    __shared__ __align__(16) char lds[32768];
    char* ldsAh = lds;
    char* ldsAl = lds + 8192;
    char* ldsBh = lds + 16384;
    char* ldsBl = lds + 24576;

    const int tid = threadIdx.x;         // 0..511
    const int lane = tid & 63;
    const int wv = tid >> 6;             // 0..7
    const int wm = wv >> 1;              // 0..3  (32-row band)
    const int wn = wv & 1;               // 0..1  (64-col band)
    const int blockRow = blockIdx.y * GBM;
    const int blockCol = blockIdx.x * GBN;

    // Staging: thread t covers row t/4, k-bytes (t%4)*16 of the 64B k-window.
    const int srow = tid >> 2;
    const int skel = (tid & 3) * 8;
    const size_t aOff = ((size_t)(blockRow + srow) * Kp + skel) * 2;
    const size_t bOff = ((size_t)(blockCol + srow) * Kp + skel) * 2;
    const char* aHp = (const char*)Ah + aOff;
    const char* aLp = (const char*)Al + aOff;
    const char* bHp = (const char*)Bh + bOff;
    const char* bLp = (const char*)Bl + bOff;
    const int stageOff = wv * 1024;      // wave-uniform LDS byte offset

    f32x4 acc[2][4];
    #pragma unroll
    for (int i = 0; i < 2; ++i)
        #pragma unroll
        for (int j = 0; j < 4; ++j)
            #pragma unroll
            for (int r = 0; r < 4; ++r) acc[i][j][r] = 0.f;

    // Fragment LDS byte offsets: row-major [128][32] bf16 tiles, 64 B rows.
    const int kq = (lane >> 4) * 16;     // 8-elem k segment of this lane
    int aFragOff[2], bFragOff[4];
    #pragma unroll
    for (int i = 0; i < 2; ++i) aFragOff[i] = (wm * 32 + i * 16 + (lane & 15)) * 64 + kq;
    #pragma unroll
    for (int j = 0; j < 4; ++j) bFragOff[j] = (wn * 64 + j * 16 + (lane & 15)) * 64 + kq;

    const int nsteps = Kp / GBK;
    for (int s = 0; s < nsteps; ++s) {
        const size_t kb = (size_t)s * GBK * 2;
        gll16(aHp + kb, ldsAh + stageOff);
        gll16(aLp + kb, ldsAl + stageOff);
        gll16(bHp + kb, ldsBh + stageOff);
        gll16(bLp + kb, ldsBl + stageOff);
        __syncthreads();

        bf16x8 ah[2], al[2], bh[4], bl[4];
        #pragma unroll
        for (int i = 0; i < 2; ++i) {
            ah[i] = *(const bf16x8*)(ldsAh + aFragOff[i]);
            al[i] = *(const bf16x8*)(ldsAl + aFragOff[i]);
        }
        #pragma unroll
        for (int j = 0; j < 4; ++j) {
            bh[j] = *(const bf16x8*)(ldsBh + bFragOff[j]);
            bl[j] = *(const bf16x8*)(ldsBl + bFragOff[j]);
        }
        #pragma unroll
        for (int j = 0; j < 4; ++j)
            #pragma unroll
            for (int i = 0; i < 2; ++i) {
                acc[i][j] = __builtin_amdgcn_mfma_f32_16x16x32_bf16(al[i], bh[j], acc[i][j], 0, 0, 0);
                acc[i][j] = __builtin_amdgcn_mfma_f32_16x16x32_bf16(ah[i], bl[j], acc[i][j], 0, 0, 0);
                acc[i][j] = __builtin_amdgcn_mfma_f32_16x16x32_bf16(ah[i], bh[j], acc[i][j], 0, 0, 0);
            }
        __syncthreads();
    }

    // Epilogue: C/D layout col=lane&15, row=(lane>>4)*4+reg  [m89-verified].
    const int rquad = (lane >> 4) * 4;
    const int cidx = lane & 15;
    #pragma unroll
    for (int i = 0; i < 2; ++i)
        #pragma unroll
        for (int j = 0; j < 4; ++j) {
            #pragma unroll
            for (int r = 0; r < 4; ++r) {
                int row = blockRow + wm * 32 + i * 16 + rquad + r;
                int col = blockCol + wn * 64 + j * 16 + cidx;
                float v = acc[i][j][r] + bias[col];
                size_t o = (size_t)row * Np + col;
                if (!storeSplit) {
                    C[o] = v;
                } else {
                    unsigned short h = f2bf_rne(v);
                    Ch[o] = h;
                    Cl[o] = f2bf_rne(v - bf2f(h));
                }
            }
        }
}

// ------------------- weight transpose + split + pad ------------------------
// W[K,N] fp32 -> H/L [Np,Kp] bf16 (row n, col k), zero-padded.
__global__ __launch_bounds__(256) void tsplit_kernel(
    const float* __restrict__ W, unsigned short* __restrict__ H, unsigned short* __restrict__ L,
    int K, int N, int Kp)
{
    __shared__ float tile[32][33];
    const int tid = threadIdx.x;
    const int tx = tid & 31, ty = tid >> 5;     // 32 x 8
    const int k0 = blockIdx.x * 32, n0 = blockIdx.y * 32;
    #pragma unroll
    for (int i = 0; i < 4; ++i) {
        int k = k0 + ty + i * 8, n = n0 + tx;
        tile[ty + i * 8][tx] = (k < K && n < N) ? W[(size_t)k * N + n] : 0.f;
    }
    __syncthreads();
    #pragma unroll
    for (int i = 0; i < 4; ++i) {
        int n = n0 + ty + i * 8, k = k0 + tx;
        float v = tile[tx][ty + i * 8];
        size_t o = (size_t)n * Kp + k;
        unsigned short h = f2bf_rne(v);
        H[o] = h;
        L[o] = f2bf_rne(v - bf2f(h));
    }
}

// -------------------- activation split + pad (rows) ------------------------
__global__ __launch_bounds__(256) void split_rows_kernel(
    const float* __restrict__ X, unsigned short* __restrict__ H, unsigned short* __restrict__ L,
    int C, int Cp)
{
    const int r = blockIdx.x;
    for (int c = threadIdx.x; c < Cp; c += 256) {
        float v = (c < C) ? X[(size_t)r * C + c] : 0.f;
        unsigned short h = f2bf_rne(v);
        size_t o = (size_t)r * Cp + c;
        H[o] = h;
        L[o] = f2bf_rne(v - bf2f(h));
    }
}

__global__ void padbias_kernel(const float* __restrict__ b, float* __restrict__ bp, int N, int Np) {
    int i = blockIdx.x * 256 + threadIdx.x;
    if (i < Np) bp[i] = (i < N) ? b[i] : 0.f;
}

// --------------------------- Quantum circuit -------------------------------
// One block per batch item; 1024-amp complex state in LDS; epilogue writes
// probs as hi/lo bf16 split (feeds the next MFMA GEMM directly).
__global__ __launch_bounds__(256) void circuit_kernel(
    const float* __restrict__ X,
    unsigned short* __restrict__ Ph, unsigned short* __restrict__ Pl,
    const float* __restrict__ W)
{
    __shared__ float re[1024];
    __shared__ float im[1024];
    __shared__ float red[4];

    const int b = blockIdx.x;
    const int tid = threadIdx.x;
    const float* xb = X + (size_t)b * 1024;

    float local = 0.f;
    #pragma unroll
    for (int i = tid; i < 1024; i += 256) {
        float v = xb[i];
        re[i] = v; im[i] = 0.f;
        local += v * v;
    }
    #pragma unroll
    for (int off = 32; off > 0; off >>= 1) local += __shfl_down(local, off);
    if ((tid & 63) == 0) red[tid >> 6] = local;
    __syncthreads();
    float inv = 1.0f / sqrtf(red[0] + red[1] + red[2] + red[3]);
    #pragma unroll
    for (int i = tid; i < 1024; i += 256) re[i] *= inv;
    __syncthreads();

    for (int l = 0; l < NL; ++l) {
        for (int q = 0; q < NQ; ++q) {
            const float* wg = W + (l * NQ + q) * 3;
            float phi = wg[0], th = wg[1], om = wg[2];
            float ch = cosf(0.5f * th), sh = sinf(0.5f * th);
            float ap = 0.5f * (phi + om), am = 0.5f * (phi - om);
            float cap = cosf(ap), sap = sinf(ap);
            float cam = cosf(am), sam = sinf(am);
            float a_re =  cap * ch, a_im = -sap * ch;
            float b_re = -cam * sh, b_im = -sam * sh;
            float c_re =  cam * sh, c_im = -sam * sh;
            float d_re =  cap * ch, d_im =  sap * ch;

            int m = 9 - q, s = 1 << m;
            #pragma unroll 2
            for (int p = tid; p < 512; p += 256) {
                int i0 = ((p >> m) << (m + 1)) | (p & (s - 1));
                int i1 = i0 | s;
                float r0 = re[i0], u0 = im[i0];
                float r1 = re[i1], u1 = im[i1];
                re[i0] = a_re * r0 - a_im * u0 + b_re * r1 - b_im * u1;
                im[i0] = a_re * u0 + a_im * r0 + b_re * u1 + b_im * r1;
                re[i1] = c_re * r0 - c_im * u0 + d_re * r1 - d_im * u1;
                im[i1] = c_re * u0 + c_im * r0 + d_re * u1 + d_im * r1;
            }
            __syncthreads();
        }
        int r = l % (NQ - 1) + 1;
        for (int q = 0; q < NQ; ++q) {
            int t = (q + r) % NQ;
            int sc = 1 << (9 - q), st = 1 << (9 - t);
            #pragma unroll 4
            for (int idx = tid; idx < 1024; idx += 256) {
                if ((idx & sc) && !(idx & st)) {
                    int j = idx | st;
                    float tr = re[idx]; re[idx] = re[j]; re[j] = tr;
                    float ti = im[idx]; im[idx] = im[j]; im[j] = ti;
                }
            }
            __syncthreads();
        }
    }

    #pragma unroll
    for (int i = tid; i < 1024; i += 256) {
        float r = re[i], u = im[i];
        float p = r * r + u * u;
        unsigned short h = f2bf_rne(p);
        size_t o = (size_t)b * 1024 + i;
        Ph[o] = h;
        Pl[o] = f2bf_rne(p - bf2f(h));
    }
}

// ------------------------- abs + row-normalize -----------------------------
__global__ __launch_bounds__(256) void absnorm_kernel(
    const float* __restrict__ X, float* __restrict__ out, int N, int stride)
{
    __shared__ float red[4];
    const int row = blockIdx.x;
    const int tid = threadIdx.x;
    const float* xr = X + (size_t)row * stride;

    float s = 0.f;
    for (int i = tid; i < N; i += 256) s += fabsf(xr[i]);
    #pragma unroll
    for (int off = 32; off > 0; off >>= 1) s += __shfl_down(s, off);
    if ((tid & 63) == 0) red[tid >> 6] = s;
    __syncthreads();
    float inv = 1.0f / (red[0] + red[1] + red[2] + red[3]);
    for (int i = tid; i < N; i += 256)
        out[(size_t)row * N + i] = fabsf(xr[i]) * inv;
}

// ---------------------------------------------------------------------------
extern "C" void kernel_launch(void* const* d_in, const int* in_sizes, int n_in,
                              void* d_out, int out_size, void* d_ws, size_t ws_size,
                              hipStream_t stream)
{
    const float* inputs = (const float*)d_in[0];
    const float* wEnc   = (const float*)d_in[1];
    const float* wDec   = (const float*)d_in[2];
    const float* W0     = (const float*)d_in[3];
    const float* b0     = (const float*)d_in[4];
    const float* W1     = (const float*)d_in[5];
    const float* b1     = (const float*)d_in[6];
    const float* W2     = (const float*)d_in[7];
    const float* b2     = (const float*)d_in[8];
    const float* W3     = (const float*)d_in[9];
    const float* b3     = (const float*)d_in[10];
    float* out = (float*)d_out;

    // ---- workspace layout (deterministic every call) ----
    char* w = (char*)d_ws;
    auto alloc = [&](size_t bytes) { char* p = w; w += (bytes + 255) & ~(size_t)255; return p; };

    unsigned short* Bt0h = (unsigned short*)alloc((size_t)1024 * 1024 * 2);
    unsigned short* Bt0l = (unsigned short*)alloc((size_t)1024 * 1024 * 2);
    unsigned short* Bt1h = (unsigned short*)alloc((size_t)2048 * 1024 * 2);
    unsigned short* Bt1l = (unsigned short*)alloc((size_t)2048 * 1024 * 2);
    unsigned short* Bt2h = (unsigned short*)alloc((size_t)1024 * 2048 * 2);
    unsigned short* Bt2l = (unsigned short*)alloc((size_t)1024 * 2048 * 2);
    unsigned short* Bt3h = (unsigned short*)alloc((size_t)1024 * 1024 * 2);
    unsigned short* Bt3l = (unsigned short*)alloc((size_t)1024 * 1024 * 2);
    float*          b3p  = (float*)alloc(1024 * 4);
    unsigned short* Ah   = (unsigned short*)alloc((size_t)B_SZ * 1024 * 2);
    unsigned short* Al   = (unsigned short*)alloc((size_t)B_SZ * 1024 * 2);
    float*          x0   = (float*)alloc((size_t)B_SZ * 1024 * 4);        // also x2
    unsigned short* ph   = (unsigned short*)alloc((size_t)B_SZ * 1024 * 2); // also p2h
    unsigned short* pl   = (unsigned short*)alloc((size_t)B_SZ * 1024 * 2); // also p2l
    unsigned short* x1h  = (unsigned short*)alloc((size_t)B_SZ * 2048 * 2);
    unsigned short* x1l  = (unsigned short*)alloc((size_t)B_SZ * 2048 * 2);
    float* x3 = (float*)Ah;   // reuse: inputs-split dead after GEMM0

    dim3 blk256(256);

    // ---- per-call weight prep (L3-resident, ~25 MB) ----
    tsplit_kernel<<<dim3(1024 / 32, 1024 / 32), blk256, 0, stream>>>(W0, Bt0h, Bt0l, 1000, 1024, 1024);
    tsplit_kernel<<<dim3(1024 / 32, 2048 / 32), blk256, 0, stream>>>(W1, Bt1h, Bt1l, 1024, 2048, 1024);
    tsplit_kernel<<<dim3(2048 / 32, 1024 / 32), blk256, 0, stream>>>(W2, Bt2h, Bt2l, 2048, 1024, 2048);
    tsplit_kernel<<<dim3(1024 / 32, 1024 / 32), blk256, 0, stream>>>(W3, Bt3h, Bt3l, 1024, 1000, 1024);
    padbias_kernel<<<4, blk256, 0, stream>>>(b3, b3p, 1000, 1024);
    split_rows_kernel<<<B_SZ, blk256, 0, stream>>>(inputs, Ah, Al, 1000, 1024);

    // ---- pipeline ----
    // x0 = inputs @ W0 + b0   [4096,1024]
    gemm3_mfma<<<dim3(1024 / GBN, B_SZ / GBM), 512, 0, stream>>>(
        Ah, Al, Bt0h, Bt0l, b0, x0, nullptr, nullptr, 1024, 1024, 0);
    // probs_enc = circuit(x0, wEnc) -> split
    circuit_kernel<<<B_SZ, blk256, 0, stream>>>(x0, ph, pl, wEnc);
    // x1 = probs @ W1 + b1    [4096,2048] -> split
    gemm3_mfma<<<dim3(2048 / GBN, B_SZ / GBM), 512, 0, stream>>>(
        ph, pl, Bt1h, Bt1l, b1, nullptr, x1h, x1l, 1024, 2048, 1);
    // x2 = x1 @ W2 + b2       [4096,1024]
    gemm3_mfma<<<dim3(1024 / GBN, B_SZ / GBM), 512, 0, stream>>>(
        x1h, x1l, Bt2h, Bt2l, b2, x0, nullptr, nullptr, 2048, 1024, 0);
    // probs_dec = circuit(x2, wDec) -> split
    circuit_kernel<<<B_SZ, blk256, 0, stream>>>(x0, ph, pl, wDec);
    // x3 = probs_dec @ W3 + b3p  [4096,1024pad]
    gemm3_mfma<<<dim3(1024 / GBN, B_SZ / GBM), 512, 0, stream>>>(
        ph, pl, Bt3h, Bt3l, b3p, x3, nullptr, nullptr, 1024, 1024, 0);
    // out = |x3| / rowsum(|x3|), first 1000 cols
    absnorm_kernel<<<B_SZ, blk256, 0, stream>>>(x3, out, 1000, 1024);
}

// Round 3
// 483.312 us; speedup vs baseline: 3.4926x; 1.2493x over previous
//
#include <hip/hip_runtime.h>
#include <math.h>

// ---------------------------------------------------------------------------
// QuantumAutoEncoder. Round 3: register-resident quantum circuit — one wave
// per batch item, 16 complex amps per lane (32 VGPRs). amp idx = (lane<<4)|reg.
// Wires 6..9 = register bits (pure VALU), wires 0..5 = lane bits (shfl_xor).
// Gate sequence compile-time unrolled; gate matrices precomputed per call.
// GEMMs unchanged from Round 2 (bf16x3 MFMA).
// ---------------------------------------------------------------------------

#define B_SZ 4096
#define EMB 1024
#define NQ 10
#define NL 3

typedef __bf16 bf16x8 __attribute__((ext_vector_type(8)));
typedef float f32x4 __attribute__((ext_vector_type(4)));
typedef unsigned short u16x8 __attribute__((ext_vector_type(8)));

__device__ __forceinline__ unsigned short f2bf_rne(float f) {
    unsigned int u = __float_as_uint(f);
    u += 0x7FFFu + ((u >> 16) & 1u);
    return (unsigned short)(u >> 16);
}
__device__ __forceinline__ float bf2f(unsigned short h) {
    return __uint_as_float(((unsigned int)h) << 16);
}

__device__ __forceinline__ void gll16(const void* g, void* l) {
    __builtin_amdgcn_global_load_lds(
        (const __attribute__((address_space(1))) void*)g,
        (__attribute__((address_space(3))) void*)l, 16, 0, 0);
}

// --------------------------- MFMA GEMM (bf16x3) ----------------------------
#define GBM 128
#define GBN 128
#define GBK 32

__global__ __launch_bounds__(512) void gemm3_mfma(
    const unsigned short* __restrict__ Ah, const unsigned short* __restrict__ Al,
    const unsigned short* __restrict__ Bh, const unsigned short* __restrict__ Bl,
    const float* __restrict__ bias,
    float* __restrict__ C, unsigned short* __restrict__ Ch, unsigned short* __restrict__ Cl,
    int Kp, int Np, int storeSplit)
{
    __shared__ __align__(16) char lds[32768];
    char* ldsAh = lds;
    char* ldsAl = lds + 8192;
    char* ldsBh = lds + 16384;
    char* ldsBl = lds + 24576;

    const int tid = threadIdx.x;
    const int lane = tid & 63;
    const int wv = tid >> 6;
    const int wm = wv >> 1;
    const int wn = wv & 1;
    const int blockRow = blockIdx.y * GBM;
    const int blockCol = blockIdx.x * GBN;

    const int srow = tid >> 2;
    const int skel = (tid & 3) * 8;
    const size_t aOff = ((size_t)(blockRow + srow) * Kp + skel) * 2;
    const size_t bOff = ((size_t)(blockCol + srow) * Kp + skel) * 2;
    const char* aHp = (const char*)Ah + aOff;
    const char* aLp = (const char*)Al + aOff;
    const char* bHp = (const char*)Bh + bOff;
    const char* bLp = (const char*)Bl + bOff;
    const int stageOff = wv * 1024;

    f32x4 acc[2][4];
    #pragma unroll
    for (int i = 0; i < 2; ++i)
        #pragma unroll
        for (int j = 0; j < 4; ++j)
            #pragma unroll
            for (int r = 0; r < 4; ++r) acc[i][j][r] = 0.f;

    const int kq = (lane >> 4) * 16;
    int aFragOff[2], bFragOff[4];
    #pragma unroll
    for (int i = 0; i < 2; ++i) aFragOff[i] = (wm * 32 + i * 16 + (lane & 15)) * 64 + kq;
    #pragma unroll
    for (int j = 0; j < 4; ++j) bFragOff[j] = (wn * 64 + j * 16 + (lane & 15)) * 64 + kq;

    const int nsteps = Kp / GBK;
    for (int s = 0; s < nsteps; ++s) {
        const size_t kb = (size_t)s * GBK * 2;
        gll16(aHp + kb, ldsAh + stageOff);
        gll16(aLp + kb, ldsAl + stageOff);
        gll16(bHp + kb, ldsBh + stageOff);
        gll16(bLp + kb, ldsBl + stageOff);
        __syncthreads();

        bf16x8 ah[2], al[2], bh[4], bl[4];
        #pragma unroll
        for (int i = 0; i < 2; ++i) {
            ah[i] = *(const bf16x8*)(ldsAh + aFragOff[i]);
            al[i] = *(const bf16x8*)(ldsAl + aFragOff[i]);
        }
        #pragma unroll
        for (int j = 0; j < 4; ++j) {
            bh[j] = *(const bf16x8*)(ldsBh + bFragOff[j]);
            bl[j] = *(const bf16x8*)(ldsBl + bFragOff[j]);
        }
        #pragma unroll
        for (int j = 0; j < 4; ++j)
            #pragma unroll
            for (int i = 0; i < 2; ++i) {
                acc[i][j] = __builtin_amdgcn_mfma_f32_16x16x32_bf16(al[i], bh[j], acc[i][j], 0, 0, 0);
                acc[i][j] = __builtin_amdgcn_mfma_f32_16x16x32_bf16(ah[i], bl[j], acc[i][j], 0, 0, 0);
                acc[i][j] = __builtin_amdgcn_mfma_f32_16x16x32_bf16(ah[i], bh[j], acc[i][j], 0, 0, 0);
            }
        __syncthreads();
    }

    const int rquad = (lane >> 4) * 4;
    const int cidx = lane & 15;
    #pragma unroll
    for (int i = 0; i < 2; ++i)
        #pragma unroll
        for (int j = 0; j < 4; ++j) {
            #pragma unroll
            for (int r = 0; r < 4; ++r) {
                int row = blockRow + wm * 32 + i * 16 + rquad + r;
                int col = blockCol + wn * 64 + j * 16 + cidx;
                float v = acc[i][j][r] + bias[col];
                size_t o = (size_t)row * Np + col;
                if (!storeSplit) {
                    C[o] = v;
                } else {
                    unsigned short h = f2bf_rne(v);
                    Ch[o] = h;
                    Cl[o] = f2bf_rne(v - bf2f(h));
                }
            }
        }
}

// ------------------- weight transpose + split + pad ------------------------
__global__ __launch_bounds__(256) void tsplit_kernel(
    const float* __restrict__ W, unsigned short* __restrict__ H, unsigned short* __restrict__ L,
    int K, int N, int Kp)
{
    __shared__ float tile[32][33];
    const int tid = threadIdx.x;
    const int tx = tid & 31, ty = tid >> 5;
    const int k0 = blockIdx.x * 32, n0 = blockIdx.y * 32;
    #pragma unroll
    for (int i = 0; i < 4; ++i) {
        int k = k0 + ty + i * 8, n = n0 + tx;
        tile[ty + i * 8][tx] = (k < K && n < N) ? W[(size_t)k * N + n] : 0.f;
    }
    __syncthreads();
    #pragma unroll
    for (int i = 0; i < 4; ++i) {
        int n = n0 + ty + i * 8, k = k0 + tx;
        float v = tile[tx][ty + i * 8];
        size_t o = (size_t)n * Kp + k;
        unsigned short h = f2bf_rne(v);
        H[o] = h;
        L[o] = f2bf_rne(v - bf2f(h));
    }
}

__global__ __launch_bounds__(256) void split_rows_kernel(
    const float* __restrict__ X, unsigned short* __restrict__ H, unsigned short* __restrict__ L,
    int C, int Cp)
{
    const int r = blockIdx.x;
    for (int c = threadIdx.x; c < Cp; c += 256) {
        float v = (c < C) ? X[(size_t)r * C + c] : 0.f;
        unsigned short h = f2bf_rne(v);
        size_t o = (size_t)r * Cp + c;
        H[o] = h;
        L[o] = f2bf_rne(v - bf2f(h));
    }
}

__global__ void padbias_kernel(const float* __restrict__ b, float* __restrict__ bp, int N, int Np) {
    int i = blockIdx.x * 256 + threadIdx.x;
    if (i < Np) bp[i] = (i < N) ? b[i] : 0.f;
}

// ----------------------- gate matrix precompute ----------------------------
// G[g*8] = {a_re,a_im,b_re,b_im,c_re,c_im,d_re,d_im}; g<30 enc, g>=30 dec.
__global__ void gatecoef_kernel(const float* __restrict__ wEnc,
                                const float* __restrict__ wDec,
                                float* __restrict__ G)
{
    int g = threadIdx.x;
    if (g >= 60) return;
    const float* w = (g < 30) ? (wEnc + g * 3) : (wDec + (g - 30) * 3);
    float phi = w[0], th = w[1], om = w[2];
    float ch = cosf(0.5f * th), sh = sinf(0.5f * th);
    float ap = 0.5f * (phi + om), am = 0.5f * (phi - om);
    float cap = cosf(ap), sap = sinf(ap);
    float cam = cosf(am), sam = sinf(am);
    float* o = G + g * 8;
    o[0] =  cap * ch; o[1] = -sap * ch;   // a = ea*c
    o[2] = -cam * sh; o[3] = -sam * sh;   // b = -eb*s
    o[4] =  cam * sh; o[5] = -sam * sh;   // c = conj(eb)*s
    o[6] =  cap * ch; o[7] =  sap * ch;   // d = conj(ea)*c
}

// ----------------- register-resident quantum circuit -----------------------
// amp idx = (lane<<4) | reg. Wire q stride S = 1<<(9-q).
// S<16  -> register bit; S>=16 -> lane bit M = S>>4.

template<int Q>
__device__ __forceinline__ void apply_rot(float (&xr)[16], float (&xi)[16],
                                          const float* __restrict__ G, int gate, int lane)
{
    const float* g = G + gate * 8;
    float are = g[0], aim = g[1], bre = g[2], bim = g[3];
    float cre = g[4], cim = g[5], dre = g[6], dim_ = g[7];
    constexpr int S = 1 << (9 - Q);
    if constexpr (S < 16) {
        #pragma unroll
        for (int p = 0; p < 8; ++p) {
            int r0 = (p / S) * (2 * S) + (p % S);   // constant-folded
            int r1 = r0 + S;
            float x0r = xr[r0], x0i = xi[r0], x1r = xr[r1], x1i = xi[r1];
            xr[r0] = are * x0r - aim * x0i + bre * x1r - bim * x1i;
            xi[r0] = are * x0i + aim * x0r + bre * x1i + bim * x1r;
            xr[r1] = cre * x0r - cim * x0i + dre * x1r - dim_ * x1i;
            xi[r1] = cre * x0i + cim * x0r + dre * x1i + dim_ * x1r;
        }
    } else {
        constexpr int M = S >> 4;
        bool bit = (lane & M) != 0;
        float pre = bit ? dre : are, pim = bit ? dim_ : aim;
        float qre = bit ? cre : bre, qim = bit ? cim : bim;
        #pragma unroll
        for (int r = 0; r < 16; ++r) {
            float ore = __shfl_xor(xr[r], M, 64);
            float oim = __shfl_xor(xi[r], M, 64);
            float nr = pre * xr[r] - pim * xi[r] + qre * ore - qim * oim;
            float ni = pre * xi[r] + pim * xr[r] + qre * oim + qim * ore;
            xr[r] = nr; xi[r] = ni;
        }
    }
}

template<int C, int T>
__device__ __forceinline__ void apply_cnot(float (&xr)[16], float (&xi)[16], int lane)
{
    constexpr int SC = 1 << (9 - C), ST = 1 << (9 - T);
    if constexpr (SC < 16 && ST < 16) {
        // both register bits: compile-time permutation (free)
        #pragma unroll
        for (int r = 0; r < 16; ++r) {
            if ((r & SC) && !(r & ST)) {
                int j = r | ST;
                float t;
                t = xr[r]; xr[r] = xr[j]; xr[j] = t;
                t = xi[r]; xi[r] = xi[j]; xi[j] = t;
            }
        }
    } else if constexpr (SC < 16) {
        // control = register bit, target = lane bit: unconditional exchange
        constexpr int MT = ST >> 4;
        #pragma unroll
        for (int r = 0; r < 16; ++r) {
            if (r & SC) {
                xr[r] = __shfl_xor(xr[r], MT, 64);
                xi[r] = __shfl_xor(xi[r], MT, 64);
            }
        }
    } else if constexpr (ST < 16) {
        // control = lane bit, target = register bit: predicated reg swap
        constexpr int MC = SC >> 4;
        bool bit = (lane & MC) != 0;
        #pragma unroll
        for (int r = 0; r < 16; ++r) {
            if (!(r & ST)) {
                int j = r | ST;
                float a0 = xr[r], a1 = xr[j];
                xr[r] = bit ? a1 : a0;  xr[j] = bit ? a0 : a1;
                float b0 = xi[r], b1 = xi[j];
                xi[r] = bit ? b1 : b0;  xi[j] = bit ? b0 : b1;
            }
        }
    } else {
        // both lane bits
        constexpr int MC = SC >> 4, MT = ST >> 4;
        bool bit = (lane & MC) != 0;
        #pragma unroll
        for (int r = 0; r < 16; ++r) {
            float o = __shfl_xor(xr[r], MT, 64);
            xr[r] = bit ? o : xr[r];
            float oi = __shfl_xor(xi[r], MT, 64);
            xi[r] = bit ? oi : xi[r];
        }
    }
}

template<int L, int Q>
__device__ __forceinline__ void rots(float (&xr)[16], float (&xi)[16],
                                     const float* __restrict__ G, int lane) {
    apply_rot<Q>(xr, xi, G, L * 10 + Q, lane);
    if constexpr (Q < 9) rots<L, Q + 1>(xr, xi, G, lane);
}
template<int L, int Q>
__device__ __forceinline__ void cnots(float (&xr)[16], float (&xi)[16], int lane) {
    constexpr int R = (L % 9) + 1;
    apply_cnot<Q, (Q + R) % 10>(xr, xi, lane);
    if constexpr (Q < 9) cnots<L, Q + 1>(xr, xi, lane);
}

__global__ __launch_bounds__(256, 4) void circuit_reg_kernel(
    const float* __restrict__ X,
    unsigned short* __restrict__ Ph, unsigned short* __restrict__ Pl,
    const float* __restrict__ G)
{
    const int lane = threadIdx.x & 63;
    const int item = blockIdx.x * 4 + (threadIdx.x >> 6);
    const size_t base = (size_t)item * 1024 + lane * 16;

    float xr[16], xi[16];
    const float4* xb = (const float4*)(X + base);
    #pragma unroll
    for (int v = 0; v < 4; ++v) {
        float4 f = xb[v];
        xr[v * 4 + 0] = f.x; xr[v * 4 + 1] = f.y;
        xr[v * 4 + 2] = f.z; xr[v * 4 + 3] = f.w;
    }
    #pragma unroll
    for (int r = 0; r < 16; ++r) xi[r] = 0.f;

    // L2 normalize across the wave
    float nrm = 0.f;
    #pragma unroll
    for (int r = 0; r < 16; ++r) nrm += xr[r] * xr[r];
    #pragma unroll
    for (int m = 32; m >= 1; m >>= 1) nrm += __shfl_xor(nrm, m, 64);
    float inv = 1.0f / sqrtf(nrm);
    #pragma unroll
    for (int r = 0; r < 16; ++r) xr[r] *= inv;

    rots<0, 0>(xr, xi, G, lane);  cnots<0, 0>(xr, xi, lane);
    rots<1, 0>(xr, xi, G, lane);  cnots<1, 0>(xr, xi, lane);
    rots<2, 0>(xr, xi, G, lane);  cnots<2, 0>(xr, xi, lane);

    // probs -> hi/lo bf16 split
    u16x8 h[2], lo[2];
    #pragma unroll
    for (int r = 0; r < 16; ++r) {
        float p = xr[r] * xr[r] + xi[r] * xi[r];
        unsigned short hh = f2bf_rne(p);
        h[r >> 3][r & 7] = hh;
        lo[r >> 3][r & 7] = f2bf_rne(p - bf2f(hh));
    }
    *(u16x8*)(Ph + base) = h[0];
    *(u16x8*)(Ph + base + 8) = h[1];
    *(u16x8*)(Pl + base) = lo[0];
    *(u16x8*)(Pl + base + 8) = lo[1];
}

// ------------------------- abs + row-normalize -----------------------------
__global__ __launch_bounds__(256) void absnorm_kernel(
    const float* __restrict__ X, float* __restrict__ out, int N, int stride)
{
    __shared__ float red[4];
    const int row = blockIdx.x;
    const int tid = threadIdx.x;
    const float* xr = X + (size_t)row * stride;

    float s = 0.f;
    for (int i = tid; i < N; i += 256) s += fabsf(xr[i]);
    #pragma unroll
    for (int off = 32; off > 0; off >>= 1) s += __shfl_down(s, off);
    if ((tid & 63) == 0) red[tid >> 6] = s;
    __syncthreads();
    float inv = 1.0f / (red[0] + red[1] + red[2] + red[3]);
    for (int i = tid; i < N; i += 256)
        out[(size_t)row * N + i] = fabsf(xr[i]) * inv;
}

// ---------------------------------------------------------------------------
extern "C" void kernel_launch(void* const* d_in, const int* in_sizes, int n_in,
                              void* d_out, int out_size, void* d_ws, size_t ws_size,
                              hipStream_t stream)
{
    const float* inputs = (const float*)d_in[0];
    const float* wEnc   = (const float*)d_in[1];
    const float* wDec   = (const float*)d_in[2];
    const float* W0     = (const float*)d_in[3];
    const float* b0     = (const float*)d_in[4];
    const float* W1     = (const float*)d_in[5];
    const float* b1     = (const float*)d_in[6];
    const float* W2     = (const float*)d_in[7];
    const float* b2     = (const float*)d_in[8];
    const float* W3     = (const float*)d_in[9];
    const float* b3     = (const float*)d_in[10];
    float* out = (float*)d_out;

    char* w = (char*)d_ws;
    auto alloc = [&](size_t bytes) { char* p = w; w += (bytes + 255) & ~(size_t)255; return p; };

    unsigned short* Bt0h = (unsigned short*)alloc((size_t)1024 * 1024 * 2);
    unsigned short* Bt0l = (unsigned short*)alloc((size_t)1024 * 1024 * 2);
    unsigned short* Bt1h = (unsigned short*)alloc((size_t)2048 * 1024 * 2);
    unsigned short* Bt1l = (unsigned short*)alloc((size_t)2048 * 1024 * 2);
    unsigned short* Bt2h = (unsigned short*)alloc((size_t)1024 * 2048 * 2);
    unsigned short* Bt2l = (unsigned short*)alloc((size_t)1024 * 2048 * 2);
    unsigned short* Bt3h = (unsigned short*)alloc((size_t)1024 * 1024 * 2);
    unsigned short* Bt3l = (unsigned short*)alloc((size_t)1024 * 1024 * 2);
    float*          b3p  = (float*)alloc(1024 * 4);
    float*          G    = (float*)alloc(60 * 8 * 4);
    unsigned short* Ah   = (unsigned short*)alloc((size_t)B_SZ * 1024 * 2);
    unsigned short* Al   = (unsigned short*)alloc((size_t)B_SZ * 1024 * 2);
    float*          x0   = (float*)alloc((size_t)B_SZ * 1024 * 4);          // also x2
    unsigned short* ph   = (unsigned short*)alloc((size_t)B_SZ * 1024 * 2);
    unsigned short* pl   = (unsigned short*)alloc((size_t)B_SZ * 1024 * 2);
    unsigned short* x1h  = (unsigned short*)alloc((size_t)B_SZ * 2048 * 2);
    unsigned short* x1l  = (unsigned short*)alloc((size_t)B_SZ * 2048 * 2);
    float* x3 = (float*)Ah;   // reuse: inputs-split dead after GEMM0

    dim3 blk256(256);

    // per-call prep
    tsplit_kernel<<<dim3(1024 / 32, 1024 / 32), blk256, 0, stream>>>(W0, Bt0h, Bt0l, 1000, 1024, 1024);
    tsplit_kernel<<<dim3(1024 / 32, 2048 / 32), blk256, 0, stream>>>(W1, Bt1h, Bt1l, 1024, 2048, 1024);
    tsplit_kernel<<<dim3(2048 / 32, 1024 / 32), blk256, 0, stream>>>(W2, Bt2h, Bt2l, 2048, 1024, 2048);
    tsplit_kernel<<<dim3(1024 / 32, 1024 / 32), blk256, 0, stream>>>(W3, Bt3h, Bt3l, 1024, 1000, 1024);
    padbias_kernel<<<4, blk256, 0, stream>>>(b3, b3p, 1000, 1024);
    gatecoef_kernel<<<1, 64, 0, stream>>>(wEnc, wDec, G);
    split_rows_kernel<<<B_SZ, blk256, 0, stream>>>(inputs, Ah, Al, 1000, 1024);

    // pipeline
    gemm3_mfma<<<dim3(1024 / GBN, B_SZ / GBM), 512, 0, stream>>>(
        Ah, Al, Bt0h, Bt0l, b0, x0, nullptr, nullptr, 1024, 1024, 0);
    circuit_reg_kernel<<<B_SZ / 4, blk256, 0, stream>>>(x0, ph, pl, G);
    gemm3_mfma<<<dim3(2048 / GBN, B_SZ / GBM), 512, 0, stream>>>(
        ph, pl, Bt1h, Bt1l, b1, nullptr, x1h, x1l, 1024, 2048, 1);
    gemm3_mfma<<<dim3(1024 / GBN, B_SZ / GBM), 512, 0, stream>>>(
        x1h, x1l, Bt2h, Bt2l, b2, x0, nullptr, nullptr, 2048, 1024, 0);
    circuit_reg_kernel<<<B_SZ / 4, blk256, 0, stream>>>(x0, ph, pl, G + 240);
    gemm3_mfma<<<dim3(1024 / GBN, B_SZ / GBM), 512, 0, stream>>>(
        ph, pl, Bt3h, Bt3l, b3p, x3, nullptr, nullptr, 1024, 1024, 0);
    absnorm_kernel<<<B_SZ, blk256, 0, stream>>>(x3, out, 1000, 1024);
}

// Round 4
// 434.596 us; speedup vs baseline: 3.8841x; 1.1121x over previous
//
#include <hip/hip_runtime.h>
#include <math.h>

// ---------------------------------------------------------------------------
// QuantumAutoEncoder. Round 4:
//  (a) split-K=2 on all batch GEMMs -> 512 blocks = 2 blocks/CU (the observed
//      600 TF-eq operating point); consumers fuse the P0+P1 partial add.
//  (b) GEMM1+GEMM2 fused algebraically: x2 = p@(W1@W2) + (b1@W2 + b2).
//      W12 precomputed per call (split-K=4), b12 by a small kernel.
// Circuits: register-resident (round 3). GEMM core: bf16x3 MFMA.
// ---------------------------------------------------------------------------

#define B_SZ 4096
#define EMB 1024
#define NQ 10
#define NL 3

typedef __bf16 bf16x8 __attribute__((ext_vector_type(8)));
typedef float f32x4 __attribute__((ext_vector_type(4)));
typedef unsigned short u16x8 __attribute__((ext_vector_type(8)));

__device__ __forceinline__ unsigned short f2bf_rne(float f) {
    unsigned int u = __float_as_uint(f);
    u += 0x7FFFu + ((u >> 16) & 1u);
    return (unsigned short)(u >> 16);
}
__device__ __forceinline__ float bf2f(unsigned short h) {
    return __uint_as_float(((unsigned int)h) << 16);
}

__device__ __forceinline__ void gll16(const void* g, void* l) {
    __builtin_amdgcn_global_load_lds(
        (const __attribute__((address_space(1))) void*)g,
        (__attribute__((address_space(3))) void*)l, 16, 0, 0);
}

// --------------------------- MFMA GEMM (bf16x3) ----------------------------
// C[M,Np] (+ zStride per K-chunk) = A[M,Kp] @ Bt[Np,Kp]^T (+ bias on z==0).
// grid = (Np/128, M/128, nz); each z computes K range [z*Ksplit,(z+1)*Ksplit).
#define GBM 128
#define GBN 128
#define GBK 32

__global__ __launch_bounds__(512) void gemm3_mfma(
    const unsigned short* __restrict__ Ah, const unsigned short* __restrict__ Al,
    const unsigned short* __restrict__ Bh, const unsigned short* __restrict__ Bl,
    const float* __restrict__ bias, float* __restrict__ C,
    int Kp, int Np, int Ksplit, size_t zStride)
{
    __shared__ __align__(16) char lds[32768];
    char* ldsAh = lds;
    char* ldsAl = lds + 8192;
    char* ldsBh = lds + 16384;
    char* ldsBl = lds + 24576;

    const int tid = threadIdx.x;
    const int lane = tid & 63;
    const int wv = tid >> 6;
    const int wm = wv >> 1;
    const int wn = wv & 1;
    const int blockRow = blockIdx.y * GBM;
    const int blockCol = blockIdx.x * GBN;
    const int z = blockIdx.z;

    const int srow = tid >> 2;
    const int skel = (tid & 3) * 8;
    const size_t aOff = ((size_t)(blockRow + srow) * Kp + skel + (size_t)z * Ksplit) * 2;
    const size_t bOff = ((size_t)(blockCol + srow) * Kp + skel + (size_t)z * Ksplit) * 2;
    const char* aHp = (const char*)Ah + aOff;
    const char* aLp = (const char*)Al + aOff;
    const char* bHp = (const char*)Bh + bOff;
    const char* bLp = (const char*)Bl + bOff;
    const int stageOff = wv * 1024;

    f32x4 acc[2][4];
    #pragma unroll
    for (int i = 0; i < 2; ++i)
        #pragma unroll
        for (int j = 0; j < 4; ++j)
            #pragma unroll
            for (int r = 0; r < 4; ++r) acc[i][j][r] = 0.f;

    const int kq = (lane >> 4) * 16;
    int aFragOff[2], bFragOff[4];
    #pragma unroll
    for (int i = 0; i < 2; ++i) aFragOff[i] = (wm * 32 + i * 16 + (lane & 15)) * 64 + kq;
    #pragma unroll
    for (int j = 0; j < 4; ++j) bFragOff[j] = (wn * 64 + j * 16 + (lane & 15)) * 64 + kq;

    const int nsteps = Ksplit / GBK;
    for (int s = 0; s < nsteps; ++s) {
        const size_t kb = (size_t)s * GBK * 2;
        gll16(aHp + kb, ldsAh + stageOff);
        gll16(aLp + kb, ldsAl + stageOff);
        gll16(bHp + kb, ldsBh + stageOff);
        gll16(bLp + kb, ldsBl + stageOff);
        __syncthreads();

        bf16x8 ah[2], al[2], bh[4], bl[4];
        #pragma unroll
        for (int i = 0; i < 2; ++i) {
            ah[i] = *(const bf16x8*)(ldsAh + aFragOff[i]);
            al[i] = *(const bf16x8*)(ldsAl + aFragOff[i]);
        }
        #pragma unroll
        for (int j = 0; j < 4; ++j) {
            bh[j] = *(const bf16x8*)(ldsBh + bFragOff[j]);
            bl[j] = *(const bf16x8*)(ldsBl + bFragOff[j]);
        }
        #pragma unroll
        for (int j = 0; j < 4; ++j)
            #pragma unroll
            for (int i = 0; i < 2; ++i) {
                acc[i][j] = __builtin_amdgcn_mfma_f32_16x16x32_bf16(al[i], bh[j], acc[i][j], 0, 0, 0);
                acc[i][j] = __builtin_amdgcn_mfma_f32_16x16x32_bf16(ah[i], bl[j], acc[i][j], 0, 0, 0);
                acc[i][j] = __builtin_amdgcn_mfma_f32_16x16x32_bf16(ah[i], bh[j], acc[i][j], 0, 0, 0);
            }
        __syncthreads();
    }

    float* Cz = C + (size_t)z * zStride;
    const bool addB = (z == 0) && (bias != nullptr);
    const int rquad = (lane >> 4) * 4;
    const int cidx = lane & 15;
    #pragma unroll
    for (int i = 0; i < 2; ++i)
        #pragma unroll
        for (int j = 0; j < 4; ++j) {
            #pragma unroll
            for (int r = 0; r < 4; ++r) {
                int row = blockRow + wm * 32 + i * 16 + rquad + r;
                int col = blockCol + wn * 64 + j * 16 + cidx;
                float v = acc[i][j][r];
                if (addB) v += bias[col];
                Cz[(size_t)row * Np + col] = v;
            }
        }
}

// ------------------- weight transpose + split + pad ------------------------
// W[K,N] fp32 -> H/L [N-ish rows, Kp] bf16 (row n, col k), zero-padded.
__global__ __launch_bounds__(256) void tsplit_kernel(
    const float* __restrict__ W, unsigned short* __restrict__ H, unsigned short* __restrict__ L,
    int K, int N, int Kp)
{
    __shared__ float tile[32][33];
    const int tid = threadIdx.x;
    const int tx = tid & 31, ty = tid >> 5;
    const int k0 = blockIdx.x * 32, n0 = blockIdx.y * 32;
    #pragma unroll
    for (int i = 0; i < 4; ++i) {
        int k = k0 + ty + i * 8, n = n0 + tx;
        tile[ty + i * 8][tx] = (k < K && n < N) ? W[(size_t)k * N + n] : 0.f;
    }
    __syncthreads();
    #pragma unroll
    for (int i = 0; i < 4; ++i) {
        int n = n0 + ty + i * 8, k = k0 + tx;
        float v = tile[tx][ty + i * 8];
        size_t o = (size_t)n * Kp + k;
        unsigned short h = f2bf_rne(v);
        H[o] = h;
        L[o] = f2bf_rne(v - bf2f(h));
    }
}

// tsplit over the sum of 4 split-K partials: P = 4 x [1024][1024] fp32.
__global__ __launch_bounds__(256) void tsplit4_kernel(
    const float* __restrict__ P, unsigned short* __restrict__ H, unsigned short* __restrict__ L)
{
    __shared__ float tile[32][33];
    const int tid = threadIdx.x;
    const int tx = tid & 31, ty = tid >> 5;
    const int k0 = blockIdx.x * 32, n0 = blockIdx.y * 32;
    #pragma unroll
    for (int i = 0; i < 4; ++i) {
        int k = k0 + ty + i * 8, n = n0 + tx;
        size_t o = (size_t)k * 1024 + n;
        tile[ty + i * 8][tx] = P[o] + P[o + (1u << 20)] + P[o + (2u << 20)] + P[o + (3u << 20)];
    }
    __syncthreads();
    #pragma unroll
    for (int i = 0; i < 4; ++i) {
        int n = n0 + ty + i * 8, k = k0 + tx;
        float v = tile[tx][ty + i * 8];
        size_t o = (size_t)n * 1024 + k;
        unsigned short h = f2bf_rne(v);
        H[o] = h;
        L[o] = f2bf_rne(v - bf2f(h));
    }
}

// -------------------- activation split + pad (rows) ------------------------
__global__ __launch_bounds__(256) void split_rows_kernel(
    const float* __restrict__ X, unsigned short* __restrict__ H, unsigned short* __restrict__ L,
    int C, int Cp)
{
    const int r = blockIdx.x;
    for (int c = threadIdx.x; c < Cp; c += 256) {
        float v = (c < C) ? X[(size_t)r * C + c] : 0.f;
        unsigned short h = f2bf_rne(v);
        size_t o = (size_t)r * Cp + c;
        H[o] = h;
        L[o] = f2bf_rne(v - bf2f(h));
    }
}

__global__ void padbias_kernel(const float* __restrict__ b, float* __restrict__ bp, int N, int Np) {
    int i = blockIdx.x * 256 + threadIdx.x;
    if (i < Np) bp[i] = (i < N) ? b[i] : 0.f;
}

// b12[n] = sum_j b1[j] * W2[j,n] + b2[n].  grid 16 x (256 = 4 j-chunks x 64 n)
__global__ __launch_bounds__(256) void b12_kernel(
    const float* __restrict__ b1, const float* __restrict__ W2,
    const float* __restrict__ b2, float* __restrict__ b12)
{
    __shared__ float red[4][64];
    const int tx = threadIdx.x & 63;
    const int ty = threadIdx.x >> 6;
    const int n = blockIdx.x * 64 + tx;
    float s = 0.f;
    for (int j = ty * 512; j < (ty + 1) * 512; ++j)
        s += b1[j] * W2[(size_t)j * 1024 + n];
    red[ty][tx] = s;
    __syncthreads();
    if (ty == 0) b12[n] = red[0][tx] + red[1][tx] + red[2][tx] + red[3][tx] + b2[n];
}

// ----------------------- gate matrix precompute ----------------------------
__global__ void gatecoef_kernel(const float* __restrict__ wEnc,
                                const float* __restrict__ wDec,
                                float* __restrict__ G)
{
    int g = threadIdx.x;
    if (g >= 60) return;
    const float* w = (g < 30) ? (wEnc + g * 3) : (wDec + (g - 30) * 3);
    float phi = w[0], th = w[1], om = w[2];
    float ch = cosf(0.5f * th), sh = sinf(0.5f * th);
    float ap = 0.5f * (phi + om), am = 0.5f * (phi - om);
    float cap = cosf(ap), sap = sinf(ap);
    float cam = cosf(am), sam = sinf(am);
    float* o = G + g * 8;
    o[0] =  cap * ch; o[1] = -sap * ch;
    o[2] = -cam * sh; o[3] = -sam * sh;
    o[4] =  cam * sh; o[5] = -sam * sh;
    o[6] =  cap * ch; o[7] =  sap * ch;
}

// ----------------- register-resident quantum circuit -----------------------
template<int Q>
__device__ __forceinline__ void apply_rot(float (&xr)[16], float (&xi)[16],
                                          const float* __restrict__ G, int gate, int lane)
{
    const float* g = G + gate * 8;
    float are = g[0], aim = g[1], bre = g[2], bim = g[3];
    float cre = g[4], cim = g[5], dre = g[6], dim_ = g[7];
    constexpr int S = 1 << (9 - Q);
    if constexpr (S < 16) {
        #pragma unroll
        for (int p = 0; p < 8; ++p) {
            int r0 = (p / S) * (2 * S) + (p % S);
            int r1 = r0 + S;
            float x0r = xr[r0], x0i = xi[r0], x1r = xr[r1], x1i = xi[r1];
            xr[r0] = are * x0r - aim * x0i + bre * x1r - bim * x1i;
            xi[r0] = are * x0i + aim * x0r + bre * x1i + bim * x1r;
            xr[r1] = cre * x0r - cim * x0i + dre * x1r - dim_ * x1i;
            xi[r1] = cre * x0i + cim * x0r + dre * x1i + dim_ * x1r;
        }
    } else {
        constexpr int M = S >> 4;
        bool bit = (lane & M) != 0;
        float pre = bit ? dre : are, pim = bit ? dim_ : aim;
        float qre = bit ? cre : bre, qim = bit ? cim : bim;
        #pragma unroll
        for (int r = 0; r < 16; ++r) {
            float ore = __shfl_xor(xr[r], M, 64);
            float oim = __shfl_xor(xi[r], M, 64);
            float nr = pre * xr[r] - pim * xi[r] + qre * ore - qim * oim;
            float ni = pre * xi[r] + pim * xr[r] + qre * oim + qim * ore;
            xr[r] = nr; xi[r] = ni;
        }
    }
}

template<int C, int T>
__device__ __forceinline__ void apply_cnot(float (&xr)[16], float (&xi)[16], int lane)
{
    constexpr int SC = 1 << (9 - C), ST = 1 << (9 - T);
    if constexpr (SC < 16 && ST < 16) {
        #pragma unroll
        for (int r = 0; r < 16; ++r) {
            if ((r & SC) && !(r & ST)) {
                int j = r | ST;
                float t;
                t = xr[r]; xr[r] = xr[j]; xr[j] = t;
                t = xi[r]; xi[r] = xi[j]; xi[j] = t;
            }
        }
    } else if constexpr (SC < 16) {
        constexpr int MT = ST >> 4;
        #pragma unroll
        for (int r = 0; r < 16; ++r) {
            if (r & SC) {
                xr[r] = __shfl_xor(xr[r], MT, 64);
                xi[r] = __shfl_xor(xi[r], MT, 64);
            }
        }
    } else if constexpr (ST < 16) {
        constexpr int MC = SC >> 4;
        bool bit = (lane & MC) != 0;
        #pragma unroll
        for (int r = 0; r < 16; ++r) {
            if (!(r & ST)) {
                int j = r | ST;
                float a0 = xr[r], a1 = xr[j];
                xr[r] = bit ? a1 : a0;  xr[j] = bit ? a0 : a1;
                float b0 = xi[r], b1 = xi[j];
                xi[r] = bit ? b1 : b0;  xi[j] = bit ? b0 : b1;
            }
        }
    } else {
        constexpr int MC = SC >> 4, MT = ST >> 4;
        bool bit = (lane & MC) != 0;
        #pragma unroll
        for (int r = 0; r < 16; ++r) {
            float o = __shfl_xor(xr[r], MT, 64);
            xr[r] = bit ? o : xr[r];
            float oi = __shfl_xor(xi[r], MT, 64);
            xi[r] = bit ? oi : xi[r];
        }
    }
}

template<int L, int Q>
__device__ __forceinline__ void rots(float (&xr)[16], float (&xi)[16],
                                     const float* __restrict__ G, int lane) {
    apply_rot<Q>(xr, xi, G, L * 10 + Q, lane);
    if constexpr (Q < 9) rots<L, Q + 1>(xr, xi, G, lane);
}
template<int L, int Q>
__device__ __forceinline__ void cnots(float (&xr)[16], float (&xi)[16], int lane) {
    constexpr int R = (L % 9) + 1;
    apply_cnot<Q, (Q + R) % 10>(xr, xi, lane);
    if constexpr (Q < 9) cnots<L, Q + 1>(xr, xi, lane);
}

// X = X0 + X1 (split-K partials), then circuit, then hi/lo bf16 split probs.
__global__ __launch_bounds__(256, 4) void circuit_reg_kernel(
    const float* __restrict__ X0, const float* __restrict__ X1,
    unsigned short* __restrict__ Ph, unsigned short* __restrict__ Pl,
    const float* __restrict__ G)
{
    const int lane = threadIdx.x & 63;
    const int item = blockIdx.x * 4 + (threadIdx.x >> 6);
    const size_t base = (size_t)item * 1024 + lane * 16;

    float xr[16], xi[16];
    const float4* xb0 = (const float4*)(X0 + base);
    const float4* xb1 = (const float4*)(X1 + base);
    #pragma unroll
    for (int v = 0; v < 4; ++v) {
        float4 f = xb0[v], g = xb1[v];
        xr[v * 4 + 0] = f.x + g.x; xr[v * 4 + 1] = f.y + g.y;
        xr[v * 4 + 2] = f.z + g.z; xr[v * 4 + 3] = f.w + g.w;
    }
    #pragma unroll
    for (int r = 0; r < 16; ++r) xi[r] = 0.f;

    float nrm = 0.f;
    #pragma unroll
    for (int r = 0; r < 16; ++r) nrm += xr[r] * xr[r];
    #pragma unroll
    for (int m = 32; m >= 1; m >>= 1) nrm += __shfl_xor(nrm, m, 64);
    float inv = 1.0f / sqrtf(nrm);
    #pragma unroll
    for (int r = 0; r < 16; ++r) xr[r] *= inv;

    rots<0, 0>(xr, xi, G, lane);  cnots<0, 0>(xr, xi, lane);
    rots<1, 0>(xr, xi, G, lane);  cnots<1, 0>(xr, xi, lane);
    rots<2, 0>(xr, xi, G, lane);  cnots<2, 0>(xr, xi, lane);

    u16x8 h[2], lo[2];
    #pragma unroll
    for (int r = 0; r < 16; ++r) {
        float p = xr[r] * xr[r] + xi[r] * xi[r];
        unsigned short hh = f2bf_rne(p);
        h[r >> 3][r & 7] = hh;
        lo[r >> 3][r & 7] = f2bf_rne(p - bf2f(hh));
    }
    *(u16x8*)(Ph + base) = h[0];
    *(u16x8*)(Ph + base + 8) = h[1];
    *(u16x8*)(Pl + base) = lo[0];
    *(u16x8*)(Pl + base + 8) = lo[1];
}

// ------------------------- abs + row-normalize -----------------------------
__global__ __launch_bounds__(256) void absnorm_kernel(
    const float* __restrict__ X0, const float* __restrict__ X1,
    float* __restrict__ out, int N, int stride)
{
    __shared__ float red[4];
    const int row = blockIdx.x;
    const int tid = threadIdx.x;
    const float* x0 = X0 + (size_t)row * stride;
    const float* x1 = X1 + (size_t)row * stride;

    float s = 0.f;
    for (int i = tid; i < N; i += 256) s += fabsf(x0[i] + x1[i]);
    #pragma unroll
    for (int off = 32; off > 0; off >>= 1) s += __shfl_down(s, off);
    if ((tid & 63) == 0) red[tid >> 6] = s;
    __syncthreads();
    float inv = 1.0f / (red[0] + red[1] + red[2] + red[3]);
    for (int i = tid; i < N; i += 256)
        out[(size_t)row * N + i] = fabsf(x0[i] + x1[i]) * inv;
}

// ---------------------------------------------------------------------------
extern "C" void kernel_launch(void* const* d_in, const int* in_sizes, int n_in,
                              void* d_out, int out_size, void* d_ws, size_t ws_size,
                              hipStream_t stream)
{
    const float* inputs = (const float*)d_in[0];
    const float* wEnc   = (const float*)d_in[1];
    const float* wDec   = (const float*)d_in[2];
    const float* W0     = (const float*)d_in[3];
    const float* b0     = (const float*)d_in[4];
    const float* W1     = (const float*)d_in[5];
    const float* b1     = (const float*)d_in[6];
    const float* W2     = (const float*)d_in[7];
    const float* b2     = (const float*)d_in[8];
    const float* W3     = (const float*)d_in[9];
    const float* b3     = (const float*)d_in[10];
    float* out = (float*)d_out;

    char* w = (char*)d_ws;
    auto alloc = [&](size_t bytes) { char* p = w; w += (bytes + 255) & ~(size_t)255; return p; };

    unsigned short* Bt0h  = (unsigned short*)alloc((size_t)1024 * 1024 * 2);
    unsigned short* Bt0l  = (unsigned short*)alloc((size_t)1024 * 1024 * 2);
    unsigned short* Bt2h  = (unsigned short*)alloc((size_t)1024 * 2048 * 2);
    unsigned short* Bt2l  = (unsigned short*)alloc((size_t)1024 * 2048 * 2);
    unsigned short* Bt3h  = (unsigned short*)alloc((size_t)1024 * 1024 * 2);
    unsigned short* Bt3l  = (unsigned short*)alloc((size_t)1024 * 1024 * 2);
    unsigned short* Bt12h = (unsigned short*)alloc((size_t)1024 * 1024 * 2);
    unsigned short* Bt12l = (unsigned short*)alloc((size_t)1024 * 1024 * 2);
    unsigned short* W1h   = (unsigned short*)alloc((size_t)1024 * 2048 * 2);
    unsigned short* W1l   = (unsigned short*)alloc((size_t)1024 * 2048 * 2);
    float*          b3p   = (float*)alloc(1024 * 4);
    float*          b12   = (float*)alloc(1024 * 4);
    float*          G     = (float*)alloc(60 * 8 * 4);
    unsigned short* Ah    = (unsigned short*)alloc((size_t)B_SZ * 1024 * 2);
    unsigned short* Al    = (unsigned short*)alloc((size_t)B_SZ * 1024 * 2);
    unsigned short* ph    = (unsigned short*)alloc((size_t)B_SZ * 1024 * 2);
    unsigned short* pl    = (unsigned short*)alloc((size_t)B_SZ * 1024 * 2);
    float*          P     = (float*)alloc((size_t)2 * B_SZ * 1024 * 4);  // split-K partials
    float* P12 = P;                 // 4 x [1024x1024] fp32 (16 MB) aliased; dead before G0
    const size_t ZS = (size_t)B_SZ * 1024;   // z-stride for batch partials (elems)

    dim3 blk256(256);

    // ---- per-call prep ----
    tsplit_kernel<<<dim3(32, 32), blk256, 0, stream>>>(W0, Bt0h, Bt0l, 1000, 1024, 1024);
    tsplit_kernel<<<dim3(64, 32), blk256, 0, stream>>>(W2, Bt2h, Bt2l, 2048, 1024, 2048);
    tsplit_kernel<<<dim3(32, 32), blk256, 0, stream>>>(W3, Bt3h, Bt3l, 1024, 1000, 1024);
    split_rows_kernel<<<1024, blk256, 0, stream>>>(W1, W1h, W1l, 2048, 2048);
    padbias_kernel<<<4, blk256, 0, stream>>>(b3, b3p, 1000, 1024);
    b12_kernel<<<16, blk256, 0, stream>>>(b1, W2, b2, b12);
    gatecoef_kernel<<<1, 64, 0, stream>>>(wEnc, wDec, G);
    split_rows_kernel<<<B_SZ, blk256, 0, stream>>>(inputs, Ah, Al, 1000, 1024);

    // ---- W12 = W1 @ W2 (split-K=4), then transpose+split -> Bt12 ----
    gemm3_mfma<<<dim3(8, 8, 4), 512, 0, stream>>>(
        W1h, W1l, Bt2h, Bt2l, nullptr, P12, 2048, 1024, 512, (size_t)1 << 20);
    tsplit4_kernel<<<dim3(32, 32), blk256, 0, stream>>>(P12, Bt12h, Bt12l);

    // ---- pipeline (batch GEMMs split-K=2, consumers add partials) ----
    gemm3_mfma<<<dim3(8, 32, 2), 512, 0, stream>>>(
        Ah, Al, Bt0h, Bt0l, b0, P, 1024, 1024, 512, ZS);
    circuit_reg_kernel<<<B_SZ / 4, blk256, 0, stream>>>(P, P + ZS, ph, pl, G);
    gemm3_mfma<<<dim3(8, 32, 2), 512, 0, stream>>>(
        ph, pl, Bt12h, Bt12l, b12, P, 1024, 1024, 512, ZS);
    circuit_reg_kernel<<<B_SZ / 4, blk256, 0, stream>>>(P, P + ZS, ph, pl, G + 240);
    gemm3_mfma<<<dim3(8, 32, 2), 512, 0, stream>>>(
        ph, pl, Bt3h, Bt3l, b3p, P, 1024, 1024, 512, ZS);
    absnorm_kernel<<<B_SZ, blk256, 0, stream>>>(P, P + ZS, out, 1000, 1024);
}